// Round 9
// baseline (1422.201 us; speedup 1.0000x reference)
//
#include <hip/hip_runtime.h>
#include <math.h>

// Problem constants (reference: S,B,I,H = 1024,512,5,32; G=4H=128)
#define S_LEN 1024
#define BATCH 512
#define HID   32

#define LOG2E 1.44269504088896340736f

__device__ __forceinline__ float fast_rcp(float x) { return __builtin_amdgcn_rcpf(x); }
__device__ __forceinline__ float fast_exp2(float x) { return __builtin_amdgcn_exp2f(x); }

// Pair barrier: make LDS writes visible across waves WITHOUT draining vmcnt
// (out stores stream; never waited in-loop).
__device__ __forceinline__ void tick_barrier() {
    asm volatile("s_waitcnt lgkmcnt(0)" ::: "memory");
    __builtin_amdgcn_s_barrier();
    asm volatile("" ::: "memory");   // compiler fence: no LDS op hoisted above
}

// gfx950 v_permlane32_swap_b32 with vdst = vsrc = v:
//   r[0] = value the HIGH half held (broadcast to all lanes' view)
//   r[1] = value the LOW  half held
typedef unsigned int uint2v __attribute__((ext_vector_type(2)));
__device__ __forceinline__ void swap_halves(float v, float& hiAll, float& loAll) {
    uint2v r = __builtin_amdgcn_permlane32_swap(__float_as_uint(v),
                                                __float_as_uint(v),
                                                false, false);
    hiAll = __uint_as_float(r[0]);
    loAll = __uint_as_float(r[1]);
}

// Broadcast lane k's value (k constant after unroll) -> SGPR operand.
__device__ __forceinline__ float bcast(float v, int k) {
    return __int_as_float(__builtin_amdgcn_readlane(__float_as_int(v), k));
}

// Load one 32-float weight row into registers, pre-scaled.
#define LOADROW(dst, base, row, sc)                                            \
    {                                                                          \
        const float4* W_ = reinterpret_cast<const float4*>((base) +            \
                                                    (size_t)(row) * HID);      \
        _Pragma("unroll")                                                      \
        for (int k4 = 0; k4 < 8; ++k4) {                                       \
            float4 v_ = W_[k4];                                                \
            dst[4 * k4 + 0] = v_.x * (sc);                                     \
            dst[4 * k4 + 1] = v_.y * (sc);                                     \
            dst[4 * k4 + 2] = v_.z * (sc);                                     \
            dst[4 * k4 + 3] = v_.w * (sc);                                     \
        }                                                                      \
    }

// Fused 3-layer LSTM + collapsed MLP head. ONE kernel, one dispatch.
// Block = 192 threads = 3 waves; wave w = layer w; blockIdx = batch element.
// 512 blocks = 2 blocks/CU: co-resident blocks interleave and hide each
// other's stalls (round-8 A/B proved this overlap is worth ~30%).
//
// LAG-2 PIPELINE: at tick t, wave w processes step s = t - 2*w. Producer h is
// consumed 2 ticks after its write, so ONE barrier per tick-PAIR suffices.
// Ring: depth-4, writer slot (t&3), reader slot (t&3)^2. Within a pair the
// written slots {t&3,(t+1)&3} and read slots are disjoint -> no intra-pair
// race; cross-pair visibility guaranteed by the pair barrier.
//
// MLP COLLAPSE: y = relu(w3.(W2(W1 h+b1)+b2)+b3) is affine in h:
//   y = relu(v.h + cbias), v = W1^T W2^T w3^T (32 floats), computed once by
// wave 2 in the prologue. Per step wave 2 reduces v.h with 5 shfl_xor and
// lane 0 streams the scalar to out. hseq + second kernel deleted.
//
// Lane l owns rows gA=l, gB=l+64 (torch order i,f,g,o):
//   lanes 0-31 (j=l):    i_j (accA), g_j (accB)
//   lanes 32-63 (j=l-32): f_j (accA), o_j (accB)
// Weights/biases pre-scaled by log2e (g rows by 2*log2e): activation is the
// uniform sigma(y)=rcp(1+exp2(-y)); tanh(g)=2*sigma(2g)-1.
// x block-slice staged in LDS once -> zero per-tick global loads.
__global__ __launch_bounds__(192)
void lstm3_fused(const float* __restrict__ x,
                 const float* __restrict__ Wih0, const float* __restrict__ Whh0,
                 const float* __restrict__ bih0, const float* __restrict__ bhh0,
                 const float* __restrict__ Wih1, const float* __restrict__ Whh1,
                 const float* __restrict__ bih1, const float* __restrict__ bhh1,
                 const float* __restrict__ Wih2, const float* __restrict__ Whh2,
                 const float* __restrict__ bih2, const float* __restrict__ bhh2,
                 const float* __restrict__ w1, const float* __restrict__ b1,
                 const float* __restrict__ w2, const float* __restrict__ b2,
                 const float* __restrict__ w3, const float* __restrict__ b3,
                 float* __restrict__ out)
{
    const int b = blockIdx.x;
    const int w = threadIdx.x >> 6;   // wave id == layer id, 0..2
    const int l = threadIdx.x & 63;
    const int j = l & 31;
    const bool lowHalf = (l < 32);
    const int gA = l;
    const int gB = l + 64;
    const float sA = LOG2E;
    const float sB = lowHalf ? (2.0f * LOG2E) : LOG2E;  // g rows get 2*log2e

    // x slice: xl4[s] = x[s][b][0..3], xl1[s] = x[s][b][4]
    __shared__ float4 xl4[S_LEN];     // 16 KB
    __shared__ float  xl1[S_LEN];     //  4 KB
    // ring[slot][src_wave][unit]; slot = tick & 3 (lag-2, depth-4)
    __shared__ float ring[4][2][HID];

    for (int i = threadIdx.x; i < 4 * 2 * HID; i += 192)
        (&ring[0][0][0])[i] = 0.0f;
    {
        float* xf = reinterpret_cast<float*>(xl4);
        for (int idx = threadIdx.x; idx < S_LEN * 5; idx += 192) {
            const int s = idx / 5;
            const int c = idx - 5 * s;
            const float v = x[(size_t)s * (BATCH * 5) + b * 5 + c];
            if (c < 4) xf[s * 4 + c] = v;
            else       xl1[s] = v;
        }
    }

    const float* Wih = (w == 0) ? Wih0 : (w == 1) ? Wih1 : Wih2;
    const float* Whh = (w == 0) ? Whh0 : (w == 1) ? Whh1 : Whh2;
    const float* bih = (w == 0) ? bih0 : (w == 1) ? bih1 : bih2;
    const float* bhh = (w == 0) ? bhh0 : (w == 1) ? bhh1 : bhh2;

    // Recurrent weight rows in registers (all waves), pre-scaled
    float whA[HID], whB[HID];
    LOADROW(whA, Whh, gA, sA);
    LOADROW(whB, Whh, gB, sB);
    // Input weight rows: wave 0 has KIN=5, waves 1/2 have KIN=32.
    float wiA[HID], wiB[HID];
    float wxA[5], wxB[5];
    if (w == 0) {
#pragma unroll
        for (int k = 0; k < 5; ++k) {
            wxA[k] = Wih[gA * 5 + k] * sA;
            wxB[k] = Wih[gB * 5 + k] * sB;
        }
    } else {
        LOADROW(wiA, Wih, gA, sA);
        LOADROW(wiB, Wih, gB, sB);
    }
    const float biasA = (bih[gA] + bhh[gA]) * sA;
    const float biasB = (bih[gB] + bhh[gB]) * sB;

    // Collapsed MLP: v_j and cbias (wave 2 only; one-time cost)
    float v_j = 0.0f, cbias = 0.0f;
    if (w == 2) {
        float uacc[HID];
#pragma unroll
        for (int k = 0; k < HID; ++k) uacc[k] = 0.0f;
        for (int r = 0; r < HID; ++r) {         // u = w3^T W2 (uniform loads)
            const float w3r = w3[r];
#pragma unroll
            for (int k = 0; k < HID; ++k)
                uacc[k] += w3r * w2[r * HID + k];
        }
#pragma unroll
        for (int k = 0; k < HID; ++k) {         // v_j = sum_k u[k] W1[k][j]
            v_j  += uacc[k] * w1[k * HID + j];
            cbias += uacc[k] * b1[k];           // + u.b1
        }
        for (int r = 0; r < HID; ++r) cbias += w3[r] * b2[r];
        cbias += b3[0];
    }

    float c = 0.0f;
    float h_own = 0.0f;   // own-layer h(t-1), unit j, identical in both halves

    __syncthreads();  // staging + ring init visible (one-time full barrier)

    for (int t = 0; t < S_LEN + 4; t += 2) {
#pragma unroll
        for (int u = 0; u < 2; ++u) {
            const int tt = t + u;
            const int s = tt - 2 * w;
            const bool active = (s >= 0) && (s < S_LEN);
            const int wslot = tt & 3;
            const int rslot = wslot ^ 2;   // written 2 ticks ago

            // ---- gate matvecs: acc = bias + Whh*h_own + Wih*input ----
            float aA0 = biasA, aA1 = 0.f, aA2 = 0.f, aA3 = 0.f;
            float aB0 = biasB, aB1 = 0.f, aB2 = 0.f, aB3 = 0.f;

            // own h via readlane broadcast (register-only, no LDS)
#pragma unroll
            for (int k4 = 0; k4 < HID / 4; ++k4) {
                const float h0 = bcast(h_own, 4 * k4 + 0);
                const float h1 = bcast(h_own, 4 * k4 + 1);
                const float h2 = bcast(h_own, 4 * k4 + 2);
                const float h3 = bcast(h_own, 4 * k4 + 3);
                aA0 += whA[4 * k4 + 0] * h0;
                aA1 += whA[4 * k4 + 1] * h1;
                aA2 += whA[4 * k4 + 2] * h2;
                aA3 += whA[4 * k4 + 3] * h3;
                aB0 += whB[4 * k4 + 0] * h0;
                aB1 += whB[4 * k4 + 1] * h1;
                aB2 += whB[4 * k4 + 2] * h2;
                aB3 += whB[4 * k4 + 3] * h3;
            }

            if (w == 0) {
                if (active) {   // wave-uniform branch
                    const float4 xv = xl4[s];
                    const float  x4 = xl1[s];
                    aA0 += wxA[0] * xv.x; aB0 += wxB[0] * xv.x;
                    aA1 += wxA[1] * xv.y; aB1 += wxB[1] * xv.y;
                    aA2 += wxA[2] * xv.z; aB2 += wxB[2] * xv.z;
                    aA3 += wxA[3] * xv.w; aB3 += wxB[3] * xv.w;
                    aA0 += wxA[4] * x4;   aB0 += wxB[4] * x4;
                }
            } else {
                // input = previous layer's h from ring (broadcast b128 reads;
                // legal at pair start: written >=2 ticks ago)
                const float4* hin4 =
                    reinterpret_cast<const float4*>(&ring[rslot][w - 1][0]);
#pragma unroll
                for (int k4 = 0; k4 < HID / 4; ++k4) {
                    float4 hv = hin4[k4];
                    aA0 += wiA[4 * k4 + 0] * hv.x;
                    aA1 += wiA[4 * k4 + 1] * hv.y;
                    aA2 += wiA[4 * k4 + 2] * hv.z;
                    aA3 += wiA[4 * k4 + 3] * hv.w;
                    aB0 += wiB[4 * k4 + 0] * hv.x;
                    aB1 += wiB[4 * k4 + 1] * hv.y;
                    aB2 += wiB[4 * k4 + 2] * hv.z;
                    aB3 += wiB[4 * k4 + 3] * hv.w;
                }
            }
            const float accA = (aA0 + aA1) + (aA2 + aA3);
            const float accB = (aB0 + aB1) + (aB2 + aB3);

            // ---- half-exchange: all lanes get all 4 gates of unit j ----
            float yf, yi, yo, yg;
            swap_halves(accA, yf, yi);   // low half held i, high half held f
            swap_halves(accB, yo, yg);   // low half held g, high half held o

            const float gi = fast_rcp(1.0f + fast_exp2(-yi));
            const float gf = fast_rcp(1.0f + fast_exp2(-yf));
            const float sg = fast_rcp(1.0f + fast_exp2(-yg));
            const float go = fast_rcp(1.0f + fast_exp2(-yo));
            const float gg = 2.0f * sg - 1.0f;  // tanh(g) = 2*sigma(2g) - 1

            const float c_new = gf * c + gi * gg;
            const float e  = fast_exp2(-2.0f * LOG2E * fabsf(c_new));
            const float tc = copysignf((1.0f - e) * fast_rcp(1.0f + e), c_new);
            const float h = go * tc;            // identical in both halves

            if (active) {
                c = c_new;
                h_own = h;                      // stays in registers
                if (w < 2) {
                    if (lowHalf) ring[wslot][w][j] = h;   // for layer w+1
                } else {
                    // collapsed MLP: y = relu(v.h + cbias); reduce 32 units
                    float prod = h * v_j;
                    prod += __shfl_xor(prod, 16);
                    prod += __shfl_xor(prod, 8);
                    prod += __shfl_xor(prod, 4);
                    prod += __shfl_xor(prod, 2);
                    prod += __shfl_xor(prod, 1);
                    const float y = fmaxf(prod + cbias, 0.0f);
                    if (l == 0)
                        out[(size_t)s * BATCH + b] = y;   // streamed, unwaited
                }
            }
        }
        tick_barrier();   // ONE barrier per tick-pair (lgkmcnt only)
    }
}

extern "C" void kernel_launch(void* const* d_in, const int* in_sizes, int n_in,
                              void* d_out, int out_size, void* d_ws, size_t ws_size,
                              hipStream_t stream)
{
    const float* x    = (const float*)d_in[0];
    const float* Wih0 = (const float*)d_in[1];
    const float* Whh0 = (const float*)d_in[2];
    const float* bih0 = (const float*)d_in[3];
    const float* bhh0 = (const float*)d_in[4];
    const float* Wih1 = (const float*)d_in[5];
    const float* Whh1 = (const float*)d_in[6];
    const float* bih1 = (const float*)d_in[7];
    const float* bhh1 = (const float*)d_in[8];
    const float* Wih2 = (const float*)d_in[9];
    const float* Whh2 = (const float*)d_in[10];
    const float* bih2 = (const float*)d_in[11];
    const float* bhh2 = (const float*)d_in[12];
    const float* w1   = (const float*)d_in[13];
    const float* b1   = (const float*)d_in[14];
    const float* w2   = (const float*)d_in[15];
    const float* b2   = (const float*)d_in[16];
    const float* w3   = (const float*)d_in[17];
    const float* b3   = (const float*)d_in[18];

    lstm3_fused<<<BATCH, 192, 0, stream>>>(x, Wih0, Whh0, bih0, bhh0,
                                           Wih1, Whh1, bih1, bhh1,
                                           Wih2, Whh2, bih2, bhh2,
                                           w1, b1, w2, b2, w3, b3,
                                           (float*)d_out);
}

// Round 10
// 961.402 us; speedup vs baseline: 1.4793x; 1.4793x over previous
//
#include <hip/hip_runtime.h>
#include <math.h>

// Problem constants (reference: S,B,I,H = 1024,512,5,32; G=4H=128)
#define S_LEN 1024
#define BATCH 512
#define HID   32

#define LOG2E 1.44269504088896340736f

__device__ __forceinline__ float fast_rcp(float x) { return __builtin_amdgcn_rcpf(x); }
__device__ __forceinline__ float fast_exp2(float x) { return __builtin_amdgcn_exp2f(x); }

// Barrier WITHOUT vmcnt drain (out stores stream; never waited in-loop).
__device__ __forceinline__ void tick_barrier() {
    asm volatile("s_waitcnt lgkmcnt(0)" ::: "memory");
    __builtin_amdgcn_s_barrier();
    asm volatile("" ::: "memory");   // compiler fence: no LDS op hoisted above
}

// gfx950 v_permlane32_swap_b32 with vdst = vsrc = v:
//   r[0] = value the HIGH half held, r[1] = value the LOW half held
typedef unsigned int uint2v __attribute__((ext_vector_type(2)));
__device__ __forceinline__ void swap_halves(float v, float& hiAll, float& loAll) {
    uint2v r = __builtin_amdgcn_permlane32_swap(__float_as_uint(v),
                                                __float_as_uint(v),
                                                false, false);
    hiAll = __uint_as_float(r[0]);
    loAll = __uint_as_float(r[1]);
}

// Broadcast lane k's value (k constant after unroll) -> SGPR operand.
__device__ __forceinline__ float bcast(float v, int k) {
    return __int_as_float(__builtin_amdgcn_readlane(__float_as_int(v), k));
}

// Load one 32-float weight row into registers, pre-scaled.
#define LOADROW(dst, base, row, sc)                                            \
    {                                                                          \
        const float4* W_ = reinterpret_cast<const float4*>((base) +            \
                                                    (size_t)(row) * HID);      \
        _Pragma("unroll")                                                      \
        for (int k4 = 0; k4 < 8; ++k4) {                                       \
            float4 v_ = W_[k4];                                                \
            dst[4 * k4 + 0] = v_.x * (sc);                                     \
            dst[4 * k4 + 1] = v_.y * (sc);                                     \
            dst[4 * k4 + 2] = v_.z * (sc);                                     \
            dst[4 * k4 + 3] = v_.w * (sc);                                     \
        }                                                                      \
    }

// Fused 3-layer LSTM + collapsed MLP head. ONE kernel, one dispatch.
// Block = 192 threads = 3 waves; wave w = layer w; blockIdx = batch element.
// 512 blocks = 2 blocks/CU co-resident (cross-block overlap hides barrier
// stalls — worth ~30%, round-8 A/B; round-9 showed it DISAPPEARS if combined
// VGPR+AGPR/wave exceeds 256, so:
//   - t-loop is #pragma unroll 1 (round-9's unroll-2 pushed regs past the
//     cliff -> 1 block/CU -> two sequential shifts -> 1.74x duration)
//   - amdgpu_waves_per_eu(2) forces the allocator to fit 2 waves/EU
//     (combined regs <= 256) as a hard guarantee.
//
// LAG-2 PIPELINE: at tick t, wave w processes step s = t - 2*w. Producer h is
// consumed exactly 2 ticks after its write -> ONE barrier per tick-PAIR:
//   writer slot (t&3), reader slot (t&3)^2 (depth-4 ring). Every cross-wave
//   read is separated from its write (and the next overwrite) by >=1 barrier
//   when barriers fire on odd ticks only.
//
// MLP COLLAPSE: y = relu(w3.(W2(W1 h+b1)+b2)+b3) is affine in h until the
// final relu: y = relu(v.h + cbias), v = W1^T(W2^T w3), computed once by
// wave 2 in its prologue. Per step: 5 shfl_xor reduce + one 4B store.
//
// Lane l owns rows gA=l, gB=l+64 (torch order i,f,g,o):
//   lanes 0-31 (j=l):    i_j (accA), g_j (accB)
//   lanes 32-63 (j=l-32): f_j (accA), o_j (accB)
// Weights/biases pre-scaled by log2e (g rows by 2*log2e): activation is the
// uniform sigma(y)=rcp(1+exp2(-y)); tanh(g)=2*sigma(2g)-1.
// x block-slice staged in LDS once -> zero per-tick global loads.
__global__ __launch_bounds__(192)
__attribute__((amdgpu_waves_per_eu(2)))
void lstm3_fused(const float* __restrict__ x,
                 const float* __restrict__ Wih0, const float* __restrict__ Whh0,
                 const float* __restrict__ bih0, const float* __restrict__ bhh0,
                 const float* __restrict__ Wih1, const float* __restrict__ Whh1,
                 const float* __restrict__ bih1, const float* __restrict__ bhh1,
                 const float* __restrict__ Wih2, const float* __restrict__ Whh2,
                 const float* __restrict__ bih2, const float* __restrict__ bhh2,
                 const float* __restrict__ w1, const float* __restrict__ b1,
                 const float* __restrict__ w2, const float* __restrict__ b2,
                 const float* __restrict__ w3, const float* __restrict__ b3,
                 float* __restrict__ out)
{
    const int b = blockIdx.x;
    const int w = threadIdx.x >> 6;   // wave id == layer id, 0..2
    const int l = threadIdx.x & 63;
    const int j = l & 31;
    const bool lowHalf = (l < 32);
    const int gA = l;
    const int gB = l + 64;
    const float sA = LOG2E;
    const float sB = lowHalf ? (2.0f * LOG2E) : LOG2E;  // g rows get 2*log2e

    // x slice: xl4[s] = x[s][b][0..3], xl1[s] = x[s][b][4]
    __shared__ float4 xl4[S_LEN];     // 16 KB
    __shared__ float  xl1[S_LEN];     //  4 KB
    // ring[slot][src_wave][unit]; slot = tick & 3 (lag-2, depth-4)
    __shared__ float ring[4][2][HID];

    for (int i = threadIdx.x; i < 4 * 2 * HID; i += 192)
        (&ring[0][0][0])[i] = 0.0f;
    {
        float* xf = reinterpret_cast<float*>(xl4);
        for (int idx = threadIdx.x; idx < S_LEN * 5; idx += 192) {
            const int s = idx / 5;
            const int c = idx - 5 * s;
            const float v = x[(size_t)s * (BATCH * 5) + b * 5 + c];
            if (c < 4) xf[s * 4 + c] = v;
            else       xl1[s] = v;
        }
    }

    const float* Wih = (w == 0) ? Wih0 : (w == 1) ? Wih1 : Wih2;
    const float* Whh = (w == 0) ? Whh0 : (w == 1) ? Whh1 : Whh2;
    const float* bih = (w == 0) ? bih0 : (w == 1) ? bih1 : bih2;
    const float* bhh = (w == 0) ? bhh0 : (w == 1) ? bhh1 : bhh2;

    // Recurrent weight rows in registers (all waves), pre-scaled
    float whA[HID], whB[HID];
    LOADROW(whA, Whh, gA, sA);
    LOADROW(whB, Whh, gB, sB);
    // Input weight rows: wave 0 has KIN=5, waves 1/2 have KIN=32.
    float wiA[HID], wiB[HID];
    float wxA[5], wxB[5];
    if (w == 0) {
#pragma unroll
        for (int k = 0; k < 5; ++k) {
            wxA[k] = Wih[gA * 5 + k] * sA;
            wxB[k] = Wih[gB * 5 + k] * sB;
        }
    } else {
        LOADROW(wiA, Wih, gA, sA);
        LOADROW(wiB, Wih, gB, sB);
    }
    const float biasA = (bih[gA] + bhh[gA]) * sA;
    const float biasB = (bih[gB] + bhh[gB]) * sB;

    // Collapsed MLP: v_j and cbias (wave 2 only; one-time prologue cost)
    float v_j = 0.0f, cbias = 0.0f;
    if (w == 2) {
        float uacc[HID];
#pragma unroll
        for (int k = 0; k < HID; ++k) uacc[k] = 0.0f;
        for (int r = 0; r < HID; ++r) {         // u = w3^T W2 (uniform loads)
            const float w3r = w3[r];
#pragma unroll
            for (int k = 0; k < HID; ++k)
                uacc[k] += w3r * w2[r * HID + k];
        }
#pragma unroll
        for (int k = 0; k < HID; ++k) {         // v_j = sum_k u[k] W1[k][j]
            v_j   += uacc[k] * w1[k * HID + j];
            cbias += uacc[k] * b1[k];           // + u.b1
        }
        for (int r = 0; r < HID; ++r) cbias += w3[r] * b2[r];
        cbias += b3[0];
    }

    float c = 0.0f;
    float h_own = 0.0f;   // own-layer h(t-1), unit j, identical in both halves

    __syncthreads();  // staging + ring init visible (one-time full barrier)

#pragma unroll 1
    for (int t = 0; t < S_LEN + 4; ++t) {
        const int s = t - 2 * w;
        const bool active = (s >= 0) && (s < S_LEN);
        const int wslot = t & 3;
        const int rslot = wslot ^ 2;   // written 2 ticks ago (previous pair)

        // ---- gate matvecs: acc = bias + Whh*h_own + Wih*input ----
        float aA0 = biasA, aA1 = 0.f, aA2 = 0.f, aA3 = 0.f;
        float aB0 = biasB, aB1 = 0.f, aB2 = 0.f, aB3 = 0.f;

        // own h via readlane broadcast (register-only, no LDS)
#pragma unroll
        for (int k4 = 0; k4 < HID / 4; ++k4) {
            const float h0 = bcast(h_own, 4 * k4 + 0);
            const float h1 = bcast(h_own, 4 * k4 + 1);
            const float h2 = bcast(h_own, 4 * k4 + 2);
            const float h3 = bcast(h_own, 4 * k4 + 3);
            aA0 += whA[4 * k4 + 0] * h0;
            aA1 += whA[4 * k4 + 1] * h1;
            aA2 += whA[4 * k4 + 2] * h2;
            aA3 += whA[4 * k4 + 3] * h3;
            aB0 += whB[4 * k4 + 0] * h0;
            aB1 += whB[4 * k4 + 1] * h1;
            aB2 += whB[4 * k4 + 2] * h2;
            aB3 += whB[4 * k4 + 3] * h3;
        }

        if (w == 0) {
            if (active) {   // wave-uniform branch
                const float4 xv = xl4[s];
                const float  x4 = xl1[s];
                aA0 += wxA[0] * xv.x; aB0 += wxB[0] * xv.x;
                aA1 += wxA[1] * xv.y; aB1 += wxB[1] * xv.y;
                aA2 += wxA[2] * xv.z; aB2 += wxB[2] * xv.z;
                aA3 += wxA[3] * xv.w; aB3 += wxB[3] * xv.w;
                aA0 += wxA[4] * x4;   aB0 += wxB[4] * x4;
            }
        } else {
            // input = previous layer's h from ring (broadcast b128 reads;
            // slot written 2 ticks ago, visible via the pair barrier)
            const float4* hin4 =
                reinterpret_cast<const float4*>(&ring[rslot][w - 1][0]);
#pragma unroll
            for (int k4 = 0; k4 < HID / 4; ++k4) {
                float4 hv = hin4[k4];
                aA0 += wiA[4 * k4 + 0] * hv.x;
                aA1 += wiA[4 * k4 + 1] * hv.y;
                aA2 += wiA[4 * k4 + 2] * hv.z;
                aA3 += wiA[4 * k4 + 3] * hv.w;
                aB0 += wiB[4 * k4 + 0] * hv.x;
                aB1 += wiB[4 * k4 + 1] * hv.y;
                aB2 += wiB[4 * k4 + 2] * hv.z;
                aB3 += wiB[4 * k4 + 3] * hv.w;
            }
        }
        const float accA = (aA0 + aA1) + (aA2 + aA3);
        const float accB = (aB0 + aB1) + (aB2 + aB3);

        // ---- half-exchange: all lanes get all 4 gates of unit j ----
        float yf, yi, yo, yg;
        swap_halves(accA, yf, yi);   // low half held i, high half held f
        swap_halves(accB, yo, yg);   // low half held g, high half held o

        const float gi = fast_rcp(1.0f + fast_exp2(-yi));
        const float gf = fast_rcp(1.0f + fast_exp2(-yf));
        const float sg = fast_rcp(1.0f + fast_exp2(-yg));
        const float go = fast_rcp(1.0f + fast_exp2(-yo));
        const float gg = 2.0f * sg - 1.0f;      // tanh(g) = 2*sigma(2g) - 1

        const float c_new = gf * c + gi * gg;
        const float e  = fast_exp2(-2.0f * LOG2E * fabsf(c_new));
        const float tc = copysignf((1.0f - e) * fast_rcp(1.0f + e), c_new);
        const float h = go * tc;                // identical in both halves

        if (active) {
            c = c_new;
            h_own = h;                          // stays in registers
            if (w < 2) {
                if (lowHalf) ring[wslot][w][j] = h;   // for layer w+1, t+2
            } else {
                // collapsed MLP: y = relu(v.h + cbias); reduce 32 units
                float prod = h * v_j;
                prod += __shfl_xor(prod, 16);
                prod += __shfl_xor(prod, 8);
                prod += __shfl_xor(prod, 4);
                prod += __shfl_xor(prod, 2);
                prod += __shfl_xor(prod, 1);
                const float y = fmaxf(prod + cbias, 0.0f);
                if (l == 0)
                    out[(size_t)s * BATCH + b] = y;   // streamed, unwaited
            }
        }
        if (t & 1) tick_barrier();   // ONE barrier per tick-pair
    }
}

extern "C" void kernel_launch(void* const* d_in, const int* in_sizes, int n_in,
                              void* d_out, int out_size, void* d_ws, size_t ws_size,
                              hipStream_t stream)
{
    const float* x    = (const float*)d_in[0];
    const float* Wih0 = (const float*)d_in[1];
    const float* Whh0 = (const float*)d_in[2];
    const float* bih0 = (const float*)d_in[3];
    const float* bhh0 = (const float*)d_in[4];
    const float* Wih1 = (const float*)d_in[5];
    const float* Whh1 = (const float*)d_in[6];
    const float* bih1 = (const float*)d_in[7];
    const float* bhh1 = (const float*)d_in[8];
    const float* Wih2 = (const float*)d_in[9];
    const float* Whh2 = (const float*)d_in[10];
    const float* bih2 = (const float*)d_in[11];
    const float* bhh2 = (const float*)d_in[12];
    const float* w1   = (const float*)d_in[13];
    const float* b1   = (const float*)d_in[14];
    const float* w2   = (const float*)d_in[15];
    const float* b2   = (const float*)d_in[16];
    const float* w3   = (const float*)d_in[17];
    const float* b3   = (const float*)d_in[18];

    lstm3_fused<<<BATCH, 192, 0, stream>>>(x, Wih0, Whh0, bih0, bhh0,
                                           Wih1, Whh1, bih1, bhh1,
                                           Wih2, Whh2, bih2, bhh2,
                                           w1, b1, w2, b2, w3, b3,
                                           (float*)d_out);
}

// Round 11
// 848.134 us; speedup vs baseline: 1.6769x; 1.1335x over previous
//
#include <hip/hip_runtime.h>
#include <math.h>

// Problem constants (reference: S,B,I,H = 1024,512,5,32; G=4H=128)
#define S_LEN 1024
#define BATCH 512
#define HID   32

#define LOG2E 1.44269504088896340736f

__device__ __forceinline__ float fast_rcp(float x) { return __builtin_amdgcn_rcpf(x); }
__device__ __forceinline__ float fast_exp2(float x) { return __builtin_amdgcn_exp2f(x); }

// Barrier WITHOUT vmcnt drain (out stores stream; never waited in-loop).
__device__ __forceinline__ void tick_barrier() {
    asm volatile("s_waitcnt lgkmcnt(0)" ::: "memory");
    __builtin_amdgcn_s_barrier();
    asm volatile("" ::: "memory");   // compiler fence: no LDS op hoisted above
}

// gfx950 v_permlane32_swap_b32 with vdst = vsrc = v:
//   r[0] = value the HIGH half held, r[1] = value the LOW half held
typedef unsigned int uint2v __attribute__((ext_vector_type(2)));
__device__ __forceinline__ void swap_halves(float v, float& hiAll, float& loAll) {
    uint2v r = __builtin_amdgcn_permlane32_swap(__float_as_uint(v),
                                                __float_as_uint(v),
                                                false, false);
    hiAll = __uint_as_float(r[0]);
    loAll = __uint_as_float(r[1]);
}

// Broadcast lane k's value (k constant after unroll) -> SGPR operand.
__device__ __forceinline__ float bcast(float v, int k) {
    return __int_as_float(__builtin_amdgcn_readlane(__float_as_int(v), k));
}

// Full-wave (64-lane) sum via DPP — VALU-ONLY (no lgkm: the pair barrier's
// lgkmcnt(0) does NOT drain it, unlike __shfl_xor which lowers to
// ds_swizzle/ds_bpermute; round-10's 5-deep shfl chain cost ~300 cyc/tick).
// LLVM atomic-optimizer sequence: 4x row_shr + row_bcast15 + row_bcast31.
// Valid total lands in LANE 63.
__device__ __forceinline__ float wave_sum64_dpp(float v) {
    float s = v;
    s += __int_as_float(__builtin_amdgcn_update_dpp(
             0, __float_as_int(s), 0x111, 0xf, 0xf, true));   // row_shr:1
    s += __int_as_float(__builtin_amdgcn_update_dpp(
             0, __float_as_int(s), 0x112, 0xf, 0xf, true));   // row_shr:2
    s += __int_as_float(__builtin_amdgcn_update_dpp(
             0, __float_as_int(s), 0x114, 0xf, 0xf, true));   // row_shr:4
    s += __int_as_float(__builtin_amdgcn_update_dpp(
             0, __float_as_int(s), 0x118, 0xf, 0xf, true));   // row_shr:8
    s += __int_as_float(__builtin_amdgcn_update_dpp(
             0, __float_as_int(s), 0x142, 0xa, 0xf, true));   // row_bcast:15 -> rows 1,3
    s += __int_as_float(__builtin_amdgcn_update_dpp(
             0, __float_as_int(s), 0x143, 0xc, 0xf, true));   // row_bcast:31 -> rows 2,3
    return s;   // lane 63 holds the 64-lane total
}

// Load one 32-float weight row into registers, pre-scaled.
#define LOADROW(dst, base, row, sc)                                            \
    {                                                                          \
        const float4* W_ = reinterpret_cast<const float4*>((base) +            \
                                                    (size_t)(row) * HID);      \
        _Pragma("unroll")                                                      \
        for (int k4 = 0; k4 < 8; ++k4) {                                       \
            float4 v_ = W_[k4];                                                \
            dst[4 * k4 + 0] = v_.x * (sc);                                     \
            dst[4 * k4 + 1] = v_.y * (sc);                                     \
            dst[4 * k4 + 2] = v_.z * (sc);                                     \
            dst[4 * k4 + 3] = v_.w * (sc);                                     \
        }                                                                      \
    }

// Fused 3-layer LSTM + collapsed MLP head. ONE kernel, one dispatch.
// Block = 192 threads = 3 waves; wave w = layer w; blockIdx = batch element.
// 512 blocks = 2 blocks/CU co-resident (cross-block overlap hides stalls;
// round-9 showed it disappears past the 256 combined-reg cliff, so the t-loop
// is #pragma unroll 1 and amdgpu_waves_per_eu(2) pins the allocator).
//
// LAG-2 PIPELINE (neutral vs lag-1 per round-10 A/B, kept for fewer barriers):
// wave w processes s = t - 2w; ring depth 4, writer slot t&3, reader (t&3)^2;
// ONE lgkmcnt-only barrier per tick-pair.
//
// MLP COLLAPSE: y = relu(v.h + cbias), v = 0.5 * W1^T(W2^T w3) — the 0.5
// compensates the 64-lane DPP sum double-counting h (replicated halves).
// Per step: 6 VALU DPP adds + one 4B store from lane 63. No lgkm ops.
//
// Lane l owns rows gA=l, gB=l+64 (torch order i,f,g,o); pre-scaled by log2e
// (g rows by 2*log2e): activation is uniform sigma(y)=rcp(1+exp2(-y));
// tanh(g)=2*sigma(2g)-1. x block-slice staged in LDS once.
__global__ __launch_bounds__(192)
__attribute__((amdgpu_waves_per_eu(2)))
void lstm3_fused(const float* __restrict__ x,
                 const float* __restrict__ Wih0, const float* __restrict__ Whh0,
                 const float* __restrict__ bih0, const float* __restrict__ bhh0,
                 const float* __restrict__ Wih1, const float* __restrict__ Whh1,
                 const float* __restrict__ bih1, const float* __restrict__ bhh1,
                 const float* __restrict__ Wih2, const float* __restrict__ Whh2,
                 const float* __restrict__ bih2, const float* __restrict__ bhh2,
                 const float* __restrict__ w1, const float* __restrict__ b1,
                 const float* __restrict__ w2, const float* __restrict__ b2,
                 const float* __restrict__ w3, const float* __restrict__ b3,
                 float* __restrict__ out)
{
    const int b = blockIdx.x;
    const int w = threadIdx.x >> 6;   // wave id == layer id, 0..2
    const int l = threadIdx.x & 63;
    const int j = l & 31;
    const bool lowHalf = (l < 32);
    const int gA = l;
    const int gB = l + 64;
    const float sA = LOG2E;
    const float sB = lowHalf ? (2.0f * LOG2E) : LOG2E;  // g rows get 2*log2e

    // x slice: xl4[s] = x[s][b][0..3], xl1[s] = x[s][b][4]
    __shared__ float4 xl4[S_LEN];     // 16 KB
    __shared__ float  xl1[S_LEN];     //  4 KB
    // ring[slot][src_wave][unit]; slot = tick & 3 (lag-2, depth-4)
    __shared__ float ring[4][2][HID];

    for (int i = threadIdx.x; i < 4 * 2 * HID; i += 192)
        (&ring[0][0][0])[i] = 0.0f;
    {
        float* xf = reinterpret_cast<float*>(xl4);
        for (int idx = threadIdx.x; idx < S_LEN * 5; idx += 192) {
            const int s = idx / 5;
            const int c = idx - 5 * s;
            const float v = x[(size_t)s * (BATCH * 5) + b * 5 + c];
            if (c < 4) xf[s * 4 + c] = v;
            else       xl1[s] = v;
        }
    }

    const float* Wih = (w == 0) ? Wih0 : (w == 1) ? Wih1 : Wih2;
    const float* Whh = (w == 0) ? Whh0 : (w == 1) ? Whh1 : Whh2;
    const float* bih = (w == 0) ? bih0 : (w == 1) ? bih1 : bih2;
    const float* bhh = (w == 0) ? bhh0 : (w == 1) ? bhh1 : bhh2;

    // Recurrent weight rows in registers (all waves), pre-scaled
    float whA[HID], whB[HID];
    LOADROW(whA, Whh, gA, sA);
    LOADROW(whB, Whh, gB, sB);
    // Input weight rows: wave 0 has KIN=5, waves 1/2 have KIN=32.
    float wiA[HID], wiB[HID];
    float wxA[5], wxB[5];
    if (w == 0) {
#pragma unroll
        for (int k = 0; k < 5; ++k) {
            wxA[k] = Wih[gA * 5 + k] * sA;
            wxB[k] = Wih[gB * 5 + k] * sB;
        }
    } else {
        LOADROW(wiA, Wih, gA, sA);
        LOADROW(wiB, Wih, gB, sB);
    }
    const float biasA = (bih[gA] + bhh[gA]) * sA;
    const float biasB = (bih[gB] + bhh[gB]) * sB;

    // Collapsed MLP: v_j (x0.5 for the 64-lane sum) and cbias (wave 2 only)
    float v_j = 0.0f, cbias = 0.0f;
    if (w == 2) {
        float uacc[HID];
#pragma unroll
        for (int k = 0; k < HID; ++k) uacc[k] = 0.0f;
        for (int r = 0; r < HID; ++r) {         // u = w3^T W2 (uniform loads)
            const float w3r = w3[r];
#pragma unroll
            for (int k = 0; k < HID; ++k)
                uacc[k] += w3r * w2[r * HID + k];
        }
#pragma unroll
        for (int k = 0; k < HID; ++k) {         // v_j = sum_k u[k] W1[k][j]
            v_j   += uacc[k] * w1[k * HID + j];
            cbias += uacc[k] * b1[k];           // + u.b1
        }
        for (int r = 0; r < HID; ++r) cbias += w3[r] * b2[r];
        cbias += b3[0];
        v_j *= 0.5f;    // halves are replicated -> 64-lane sum double-counts
    }

    float c = 0.0f;
    float h_own = 0.0f;   // own-layer h(t-1), unit j, identical in both halves

    __syncthreads();  // staging + ring init visible (one-time full barrier)

#pragma unroll 1
    for (int t = 0; t < S_LEN + 4; ++t) {
        const int s = t - 2 * w;
        const bool active = (s >= 0) && (s < S_LEN);
        const int wslot = t & 3;
        const int rslot = wslot ^ 2;   // written 2 ticks ago (previous pair)

        // ---- gate matvecs: acc = bias + Whh*h_own + Wih*input ----
        float aA0 = biasA, aA1 = 0.f, aA2 = 0.f, aA3 = 0.f;
        float aB0 = biasB, aB1 = 0.f, aB2 = 0.f, aB3 = 0.f;

        // own h via readlane broadcast (register-only, no LDS)
#pragma unroll
        for (int k4 = 0; k4 < HID / 4; ++k4) {
            const float h0 = bcast(h_own, 4 * k4 + 0);
            const float h1 = bcast(h_own, 4 * k4 + 1);
            const float h2 = bcast(h_own, 4 * k4 + 2);
            const float h3 = bcast(h_own, 4 * k4 + 3);
            aA0 += whA[4 * k4 + 0] * h0;
            aA1 += whA[4 * k4 + 1] * h1;
            aA2 += whA[4 * k4 + 2] * h2;
            aA3 += whA[4 * k4 + 3] * h3;
            aB0 += whB[4 * k4 + 0] * h0;
            aB1 += whB[4 * k4 + 1] * h1;
            aB2 += whB[4 * k4 + 2] * h2;
            aB3 += whB[4 * k4 + 3] * h3;
        }

        if (w == 0) {
            if (active) {   // wave-uniform branch
                const float4 xv = xl4[s];
                const float  x4 = xl1[s];
                aA0 += wxA[0] * xv.x; aB0 += wxB[0] * xv.x;
                aA1 += wxA[1] * xv.y; aB1 += wxB[1] * xv.y;
                aA2 += wxA[2] * xv.z; aB2 += wxB[2] * xv.z;
                aA3 += wxA[3] * xv.w; aB3 += wxB[3] * xv.w;
                aA0 += wxA[4] * x4;   aB0 += wxB[4] * x4;
            }
        } else {
            // input = previous layer's h from ring (broadcast b128 reads;
            // slot written 2 ticks ago, visible via the pair barrier)
            const float4* hin4 =
                reinterpret_cast<const float4*>(&ring[rslot][w - 1][0]);
#pragma unroll
            for (int k4 = 0; k4 < HID / 4; ++k4) {
                float4 hv = hin4[k4];
                aA0 += wiA[4 * k4 + 0] * hv.x;
                aA1 += wiA[4 * k4 + 1] * hv.y;
                aA2 += wiA[4 * k4 + 2] * hv.z;
                aA3 += wiA[4 * k4 + 3] * hv.w;
                aB0 += wiB[4 * k4 + 0] * hv.x;
                aB1 += wiB[4 * k4 + 1] * hv.y;
                aB2 += wiB[4 * k4 + 2] * hv.z;
                aB3 += wiB[4 * k4 + 3] * hv.w;
            }
        }
        const float accA = (aA0 + aA1) + (aA2 + aA3);
        const float accB = (aB0 + aB1) + (aB2 + aB3);

        // ---- half-exchange: all lanes get all 4 gates of unit j ----
        float yf, yi, yo, yg;
        swap_halves(accA, yf, yi);   // low half held i, high half held f
        swap_halves(accB, yo, yg);   // low half held g, high half held o

        const float gi = fast_rcp(1.0f + fast_exp2(-yi));
        const float gf = fast_rcp(1.0f + fast_exp2(-yf));
        const float sg = fast_rcp(1.0f + fast_exp2(-yg));
        const float go = fast_rcp(1.0f + fast_exp2(-yo));
        const float gg = 2.0f * sg - 1.0f;      // tanh(g) = 2*sigma(2g) - 1

        const float c_new = gf * c + gi * gg;
        const float e  = fast_exp2(-2.0f * LOG2E * fabsf(c_new));
        const float tc = copysignf((1.0f - e) * fast_rcp(1.0f + e), c_new);
        const float h = go * tc;                // identical in both halves

        if (active) {
            c = c_new;
            h_own = h;                          // stays in registers
            if (w < 2) {
                if (lowHalf) ring[wslot][w][j] = h;   // for layer w+1, t+2
            } else {
                // collapsed MLP: y = relu(v.h + cbias), VALU-only DPP reduce
                const float tot = wave_sum64_dpp(h * v_j);
                const float y = fmaxf(tot + cbias, 0.0f);
                if (l == 63)
                    out[(size_t)s * BATCH + b] = y;   // streamed, unwaited
            }
        }
        if (t & 1) tick_barrier();   // ONE barrier per tick-pair
    }
}

extern "C" void kernel_launch(void* const* d_in, const int* in_sizes, int n_in,
                              void* d_out, int out_size, void* d_ws, size_t ws_size,
                              hipStream_t stream)
{
    const float* x    = (const float*)d_in[0];
    const float* Wih0 = (const float*)d_in[1];
    const float* Whh0 = (const float*)d_in[2];
    const float* bih0 = (const float*)d_in[3];
    const float* bhh0 = (const float*)d_in[4];
    const float* Wih1 = (const float*)d_in[5];
    const float* Whh1 = (const float*)d_in[6];
    const float* bih1 = (const float*)d_in[7];
    const float* bhh1 = (const float*)d_in[8];
    const float* Wih2 = (const float*)d_in[9];
    const float* Whh2 = (const float*)d_in[10];
    const float* bih2 = (const float*)d_in[11];
    const float* bhh2 = (const float*)d_in[12];
    const float* w1   = (const float*)d_in[13];
    const float* b1   = (const float*)d_in[14];
    const float* w2   = (const float*)d_in[15];
    const float* b2   = (const float*)d_in[16];
    const float* w3   = (const float*)d_in[17];
    const float* b3   = (const float*)d_in[18];

    lstm3_fused<<<BATCH, 192, 0, stream>>>(x, Wih0, Whh0, bih0, bhh0,
                                           Wih1, Whh1, bih1, bhh1,
                                           Wih2, Whh2, bih2, bhh2,
                                           w1, b1, w2, b2, w3, b3,
                                           (float*)d_out);
}